// Round 1
// baseline (356.605 us; speedup 1.0000x reference)
//
#include <hip/hip_runtime.h>

#define S_Q 512
#define DIM 512
#define SEGF 64
#define SCALE_F 0.04419417382415922f  // 1/sqrt(512)

__device__ __forceinline__ float wave_reduce_sum(float v) {
#pragma unroll
  for (int off = 32; off > 0; off >>= 1) v += __shfl_xor(v, off);
  return v;
}
__device__ __forceinline__ float wave_reduce_max(float v) {
#pragma unroll
  for (int off = 32; off > 0; off >>= 1) v = fmaxf(v, __shfl_xor(v, off));
  return v;
}

// ---------------------------------------------------------------------------
// K1: cross-attention partials. One block per 64-frame segment j.
// Computes partial softmax (m, sumexp) and partial weighted sums of `memory`
// for the 3 queries (j-1, j, j+1) that attend this segment.
// memory+pos each read from HBM exactly once across the whole grid.
// ---------------------------------------------------------------------------
__global__ __launch_bounds__(256) void k_ca_partial(
    const float* __restrict__ tgt, const float* __restrict__ qpos,
    const float* __restrict__ mem, const float* __restrict__ pos,
    float* __restrict__ part_acc, float* __restrict__ part_ms) {
  const int j = blockIdx.x;
  const int tid = threadIdx.x;
  const int wave = tid >> 6;
  const int lane = tid & 63;
  __shared__ float sc[3][64];
  __shared__ float pe[3][64];
  __shared__ float msh[3][2];

  const int d0 = lane * 8;
  float qf[3][8];
#pragma unroll
  for (int c = 0; c < 3; ++c) {
    const int qi = j - 1 + c;
    if ((unsigned)qi < (unsigned)S_Q) {
      const float4* tp = (const float4*)(tgt + (size_t)qi * DIM + d0);
      const float4* qp = (const float4*)(qpos + (size_t)qi * DIM + d0);
      float4 t0 = tp[0], t1 = tp[1], q0 = qp[0], q1 = qp[1];
      qf[c][0] = t0.x + q0.x; qf[c][1] = t0.y + q0.y;
      qf[c][2] = t0.z + q0.z; qf[c][3] = t0.w + q0.w;
      qf[c][4] = t1.x + q1.x; qf[c][5] = t1.y + q1.y;
      qf[c][6] = t1.z + q1.z; qf[c][7] = t1.w + q1.w;
    } else {
#pragma unroll
      for (int e = 0; e < 8; ++e) qf[c][e] = 0.f;
    }
  }

  // Phase A: scores for 64 frames x 3 queries. Wave w owns frames [16w,16w+16).
  for (int it = 0; it < 16; ++it) {
    const int t = wave * 16 + it;
    const size_t f = (size_t)j * SEGF + t;
    const float4* mp = (const float4*)(mem + f * DIM + d0);
    const float4* pp = (const float4*)(pos + f * DIM + d0);
    float4 m0 = mp[0], m1 = mp[1], p0 = pp[0], p1 = pp[1];
    float kk[8] = {m0.x + p0.x, m0.y + p0.y, m0.z + p0.z, m0.w + p0.w,
                   m1.x + p1.x, m1.y + p1.y, m1.z + p1.z, m1.w + p1.w};
    float s0 = 0.f, s1 = 0.f, s2 = 0.f;
#pragma unroll
    for (int e = 0; e < 8; ++e) {
      s0 += qf[0][e] * kk[e];
      s1 += qf[1][e] * kk[e];
      s2 += qf[2][e] * kk[e];
    }
#pragma unroll
    for (int off = 32; off > 0; off >>= 1) {
      s0 += __shfl_xor(s0, off);
      s1 += __shfl_xor(s1, off);
      s2 += __shfl_xor(s2, off);
    }
    if (lane == 0) {
      sc[0][t] = s0 * SCALE_F;
      sc[1][t] = s1 * SCALE_F;
      sc[2][t] = s2 * SCALE_F;
    }
  }
  __syncthreads();

  // Phase B: per-query partial softmax stats over this segment's 64 scores.
  if (wave < 3) {
    float v = sc[wave][lane];
    float m = wave_reduce_max(v);
    float e = __expf(v - m);
    float s = wave_reduce_sum(e);
    pe[wave][lane] = e;
    if (lane == 0) { msh[wave][0] = m; msh[wave][1] = s; }
  }
  __syncthreads();

  // Phase C: partial weighted sum of memory rows (re-read hits L2).
  const int d = tid * 2;
  float a00 = 0.f, a01 = 0.f, a10 = 0.f, a11 = 0.f, a20 = 0.f, a21 = 0.f;
  for (int t = 0; t < SEGF; ++t) {
    const size_t f = (size_t)j * SEGF + t;
    float2 mv = *(const float2*)(mem + f * DIM + d);
    float p0 = pe[0][t], p1 = pe[1][t], p2 = pe[2][t];
    a00 += p0 * mv.x; a01 += p0 * mv.y;
    a10 += p1 * mv.x; a11 += p1 * mv.y;
    a20 += p2 * mv.x; a21 += p2 * mv.y;
  }
  const float accs[3][2] = {{a00, a01}, {a10, a11}, {a20, a21}};
#pragma unroll
  for (int c = 0; c < 3; ++c) {
    const int qi = j - 1 + c;
    if ((unsigned)qi < (unsigned)S_Q) {
      *(float2*)(part_acc + ((size_t)qi * 3 + c) * DIM + d) =
          make_float2(accs[c][0], accs[c][1]);
      if (tid == 0) {
        part_ms[((size_t)qi * 3 + c) * 2 + 0] = msh[c][0];
        part_ms[((size_t)qi * 3 + c) * 2 + 1] = msh[c][1];
      }
    }
  }
}

// ---------------------------------------------------------------------------
// K2: combine the <=3 segment partials per query, finish softmax, apply ReLU.
// Slot c for query i was produced by segment j = i - 1 + c... inverse: the
// block for segment j wrote query (j-1+c) at slot c, so query i has slot 0
// from segment i+1, slot 1 from segment i, slot 2 from segment i-1.
// ---------------------------------------------------------------------------
__global__ __launch_bounds__(256) void k_ca_combine(
    const float* __restrict__ part_acc, const float* __restrict__ part_ms,
    float* __restrict__ t2r) {
  const int i = blockIdx.x;
  const int tid = threadIdx.x;
  const bool v0 = (i < S_Q - 1);  // slot 0 valid (segment i+1 exists)
  const bool v2 = (i > 0);        // slot 2 valid (segment i-1 exists)
  float m0 = -3.0e38f, m2 = -3.0e38f, s0 = 0.f, s2 = 0.f;
  if (v0) { m0 = part_ms[((size_t)i * 3 + 0) * 2]; s0 = part_ms[((size_t)i * 3 + 0) * 2 + 1]; }
  const float m1 = part_ms[((size_t)i * 3 + 1) * 2];
  const float s1 = part_ms[((size_t)i * 3 + 1) * 2 + 1];
  if (v2) { m2 = part_ms[((size_t)i * 3 + 2) * 2]; s2 = part_ms[((size_t)i * 3 + 2) * 2 + 1]; }
  const float M = fmaxf(m1, fmaxf(m0, m2));
  const float w0 = v0 ? __expf(m0 - M) : 0.f;
  const float w1 = __expf(m1 - M);
  const float w2 = v2 ? __expf(m2 - M) : 0.f;
  const float inv = 1.f / (w0 * s0 + w1 * s1 + w2 * s2);
  const int d = tid * 2;
  float ox = 0.f, oy = 0.f;
  if (v0) {
    float2 a = *(const float2*)(part_acc + ((size_t)i * 3 + 0) * DIM + d);
    ox += w0 * a.x; oy += w0 * a.y;
  }
  {
    float2 a = *(const float2*)(part_acc + ((size_t)i * 3 + 1) * DIM + d);
    ox += w1 * a.x; oy += w1 * a.y;
  }
  if (v2) {
    float2 a = *(const float2*)(part_acc + ((size_t)i * 3 + 2) * DIM + d);
    ox += w2 * a.x; oy += w2 * a.y;
  }
  ox = fmaxf(ox * inv, 0.f);
  oy = fmaxf(oy * inv, 0.f);
  *(float2*)(t2r + (size_t)i * DIM + d) = make_float2(ox, oy);
}

// ---------------------------------------------------------------------------
// Tiled fp32 GEMM: C[i][o] = sum_k A[i][k] * W[o][k] + bias[o], optional ReLU.
// 512x512x512, 32x32 tiles, grid 16x16 = 256 blocks (1 per CU).
// ---------------------------------------------------------------------------
template <bool RELU>
__global__ __launch_bounds__(256) void k_gemm512(
    const float* __restrict__ A, const float* __restrict__ W,
    const float* __restrict__ bias, float* __restrict__ C) {
  __shared__ float As[32][33];
  __shared__ float Ws[32][33];
  const int tid = threadIdx.x;
  const int bx = blockIdx.x, by = blockIdx.y;
  const int lr = tid >> 3, lq = (tid & 7) * 4;
  const int tx = tid & 15, ty = tid >> 4;
  const float* Ag = A + (size_t)(by * 32 + lr) * DIM + lq;
  const float* Wg = W + (size_t)(bx * 32 + lr) * DIM + lq;
  float acc00 = 0.f, acc01 = 0.f, acc10 = 0.f, acc11 = 0.f;
  for (int kc = 0; kc < DIM; kc += 32) {
    float4 av = *(const float4*)(Ag + kc);
    float4 wv = *(const float4*)(Wg + kc);
    __syncthreads();
    As[lr][lq] = av.x; As[lr][lq + 1] = av.y; As[lr][lq + 2] = av.z; As[lr][lq + 3] = av.w;
    Ws[lr][lq] = wv.x; Ws[lr][lq + 1] = wv.y; Ws[lr][lq + 2] = wv.z; Ws[lr][lq + 3] = wv.w;
    __syncthreads();
    const float* ar0 = &As[ty * 2][0];
    const float* ar1 = &As[ty * 2 + 1][0];
    const float* wr0 = &Ws[tx * 2][0];
    const float* wr1 = &Ws[tx * 2 + 1][0];
#pragma unroll
    for (int k = 0; k < 32; ++k) {
      float a0 = ar0[k], a1 = ar1[k], w0 = wr0[k], w1 = wr1[k];
      acc00 += a0 * w0; acc01 += a0 * w1;
      acc10 += a1 * w0; acc11 += a1 * w1;
    }
  }
  const int row = by * 32 + ty * 2, col = bx * 32 + tx * 2;
  const float b0 = bias[col], b1 = bias[col + 1];
  float r00 = acc00 + b0, r01 = acc01 + b1, r10 = acc10 + b0, r11 = acc11 + b1;
  if (RELU) {
    r00 = fmaxf(r00, 0.f); r01 = fmaxf(r01, 0.f);
    r10 = fmaxf(r10, 0.f); r11 = fmaxf(r11, 0.f);
  }
  C[(size_t)row * DIM + col] = r00;
  C[(size_t)row * DIM + col + 1] = r01;
  C[(size_t)(row + 1) * DIM + col] = r10;
  C[(size_t)(row + 1) * DIM + col + 1] = r11;
}

// ---------------------------------------------------------------------------
// Residual add + LayerNorm. One wave per 512-float row, 4 rows per block.
// ---------------------------------------------------------------------------
__global__ __launch_bounds__(256) void k_addln(
    const float* __restrict__ X, const float* __restrict__ R,
    const float* __restrict__ g, const float* __restrict__ b,
    float* __restrict__ out) {
  const int row = blockIdx.x * 4 + (threadIdx.x >> 6);
  const int lane = threadIdx.x & 63;
  const int d = lane * 8;
  const float4* xp = (const float4*)(X + (size_t)row * DIM + d);
  const float4* rp = (const float4*)(R + (size_t)row * DIM + d);
  float4 x0 = xp[0], x1 = xp[1], r0 = rp[0], r1 = rp[1];
  float v[8] = {x0.x + r0.x, x0.y + r0.y, x0.z + r0.z, x0.w + r0.w,
                x1.x + r1.x, x1.y + r1.y, x1.z + r1.z, x1.w + r1.w};
  float s = 0.f, sq = 0.f;
#pragma unroll
  for (int e = 0; e < 8; ++e) { s += v[e]; sq += v[e] * v[e]; }
  s = wave_reduce_sum(s);
  sq = wave_reduce_sum(sq);
  const float mean = s * (1.f / DIM);
  const float var = sq * (1.f / DIM) - mean * mean;
  const float rstd = rsqrtf(var + 1e-5f);
  const float4* gp = (const float4*)(g + d);
  const float4* bp = (const float4*)(b + d);
  float4 g0 = gp[0], g1 = gp[1], bb0 = bp[0], bb1 = bp[1];
  float4 o0, o1;
  o0.x = (v[0] - mean) * rstd * g0.x + bb0.x;
  o0.y = (v[1] - mean) * rstd * g0.y + bb0.y;
  o0.z = (v[2] - mean) * rstd * g0.z + bb0.z;
  o0.w = (v[3] - mean) * rstd * g0.w + bb0.w;
  o1.x = (v[4] - mean) * rstd * g1.x + bb1.x;
  o1.y = (v[5] - mean) * rstd * g1.y + bb1.y;
  o1.z = (v[6] - mean) * rstd * g1.z + bb1.z;
  o1.w = (v[7] - mean) * rstd * g1.w + bb1.w;
  *(float4*)(out + (size_t)row * DIM + d) = o0;
  *(float4*)(out + (size_t)row * DIM + d + 4) = o1;
}

// ---------------------------------------------------------------------------
// Banded self-attention (+/-4) + ReLU, one block per query.
// ---------------------------------------------------------------------------
__global__ __launch_bounds__(256) void k_sa_attn(const float* __restrict__ X,
                                                 float* __restrict__ outr) {
  const int i = blockIdx.x;
  const int tid = threadIdx.x;
  const int wave = tid >> 6, lane = tid & 63;
  const int jlo = (i - 4 > 0) ? i - 4 : 0;
  const int jhi = (i + 4 < S_Q - 1) ? i + 4 : S_Q - 1;
  const int n = jhi - jlo + 1;
  __shared__ float sc[9];
  const int d0 = lane * 8;
  const float4* qp = (const float4*)(X + (size_t)i * DIM + d0);
  float4 q0 = qp[0], q1 = qp[1];
  for (int idx = wave; idx < n; idx += 4) {
    const float4* kp = (const float4*)(X + (size_t)(jlo + idx) * DIM + d0);
    float4 k0 = kp[0], k1 = kp[1];
    float s = q0.x * k0.x + q0.y * k0.y + q0.z * k0.z + q0.w * k0.w +
              q1.x * k1.x + q1.y * k1.y + q1.z * k1.z + q1.w * k1.w;
    s = wave_reduce_sum(s);
    if (lane == 0) sc[idx] = s * SCALE_F;
  }
  __syncthreads();
  float m = -3.0e38f;
#pragma unroll
  for (int k = 0; k < 9; ++k)
    if (k < n) m = fmaxf(m, sc[k]);
  float p[9];
  float den = 0.f;
#pragma unroll
  for (int k = 0; k < 9; ++k) {
    p[k] = (k < n) ? __expf(sc[k] - m) : 0.f;
    den += p[k];
  }
  const float inv = 1.f / den;
  const int d = tid * 2;
  float ox = 0.f, oy = 0.f;
#pragma unroll
  for (int k = 0; k < 9; ++k) {
    if (k < n) {
      float2 xv = *(const float2*)(X + (size_t)(jlo + k) * DIM + d);
      ox += p[k] * xv.x;
      oy += p[k] * xv.y;
    }
  }
  ox = fmaxf(ox * inv, 0.f);
  oy = fmaxf(oy * inv, 0.f);
  *(float2*)(outr + (size_t)i * DIM + d) = make_float2(ox, oy);
}

// ---------------------------------------------------------------------------
extern "C" void kernel_launch(void* const* d_in, const int* in_sizes, int n_in,
                              void* d_out, int out_size, void* d_ws, size_t ws_size,
                              hipStream_t stream) {
  const float* tgt       = (const float*)d_in[0];
  const float* memory    = (const float*)d_in[1];
  const float* pos       = (const float*)d_in[2];
  const float* qpos      = (const float*)d_in[3];
  // d_in[4] action_idx: analytically t/64, unused
  const float* ca_t2l_w  = (const float*)d_in[5];
  const float* ca_t2l_b  = (const float*)d_in[6];
  const float* ca_l1_w   = (const float*)d_in[7];
  const float* ca_l1_b   = (const float*)d_in[8];
  const float* ca_l2_w   = (const float*)d_in[9];
  const float* ca_l2_b   = (const float*)d_in[10];
  const float* ca_n2_g   = (const float*)d_in[11];
  const float* ca_n2_b   = (const float*)d_in[12];
  const float* ca_n3_g   = (const float*)d_in[13];
  const float* ca_n3_b   = (const float*)d_in[14];
  const float* sa_conv_w = (const float*)d_in[15];
  const float* sa_conv_b = (const float*)d_in[16];
  const float* sa_l1_w   = (const float*)d_in[17];
  const float* sa_l1_b   = (const float*)d_in[18];
  const float* sa_l2_w   = (const float*)d_in[19];
  const float* sa_l2_b   = (const float*)d_in[20];
  const float* sa_n1_g   = (const float*)d_in[21];
  const float* sa_n1_b   = (const float*)d_in[22];
  const float* sa_n2_g   = (const float*)d_in[23];
  const float* sa_n2_b   = (const float*)d_in[24];
  float* out = (float*)d_out;
  float* ws = (float*)d_ws;

  // workspace layout (floats). Partials are dead after k_ca_combine, so the
  // activation buffers buf1..buf3 alias the partial region. Peak: 4.02 MB.
  float* part_acc = ws;              // [512][3][512] = 786432
  float* part_ms  = ws + 786432;     // [512][3][2]   = 3072
  float* bufA     = ws + 789504;     // 262144 (never aliased)
  float* buf1     = ws;              // 262144 (aliases dead part_acc)
  float* buf2     = ws + 262144;     // 262144
  float* buf3     = ws + 524288;     // 262144

  const dim3 gg(16, 16, 1);

  // ---- cross attention ----
  k_ca_partial<<<512, 256, 0, stream>>>(tgt, qpos, memory, pos, part_acc, part_ms);
  k_ca_combine<<<512, 256, 0, stream>>>(part_acc, part_ms, bufA);       // relu(tgt2_attn)
  k_gemm512<false><<<gg, 256, 0, stream>>>(bufA, ca_t2l_w, ca_t2l_b, buf1);
  k_addln<<<128, 256, 0, stream>>>(buf1, tgt, ca_n2_g, ca_n2_b, buf2);  // x
  k_gemm512<true><<<gg, 256, 0, stream>>>(buf2, ca_l1_w, ca_l1_b, bufA);   // h
  k_gemm512<false><<<gg, 256, 0, stream>>>(bufA, ca_l2_w, ca_l2_b, buf1);
  k_addln<<<128, 256, 0, stream>>>(buf1, buf2, ca_n3_g, ca_n3_b, buf3); // x2
  // ---- self attention ----
  k_sa_attn<<<512, 256, 0, stream>>>(buf3, bufA);                       // relu(src2_attn)
  k_gemm512<false><<<gg, 256, 0, stream>>>(bufA, sa_conv_w, sa_conv_b, buf1);
  k_addln<<<128, 256, 0, stream>>>(buf1, buf3, sa_n1_g, sa_n1_b, buf2); // y1
  k_gemm512<true><<<gg, 256, 0, stream>>>(buf2, sa_l1_w, sa_l1_b, bufA);   // h2
  k_gemm512<false><<<gg, 256, 0, stream>>>(bufA, sa_l2_w, sa_l2_b, buf1);
  k_addln<<<128, 256, 0, stream>>>(buf1, buf2, sa_n2_g, sa_n2_b, out);
}

// Round 2
// 300.093 us; speedup vs baseline: 1.1883x; 1.1883x over previous
//
#include <hip/hip_runtime.h>

#define S_Q 512
#define DIM 512
#define SCALE_F 0.04419417382415922f  // 1/sqrt(512)

typedef short short8 __attribute__((ext_vector_type(8)));
typedef float floatx4 __attribute__((ext_vector_type(4)));

__device__ __forceinline__ float wave_reduce_sum(float v) {
#pragma unroll
  for (int off = 32; off > 0; off >>= 1) v += __shfl_xor(v, off);
  return v;
}

__device__ __forceinline__ unsigned short f2bf(float f) {
  unsigned int u = __float_as_uint(f);
  return (unsigned short)((u + 0x7FFFu + ((u >> 16) & 1u)) >> 16);
}

// ---------------------------------------------------------------------------
// K1: cross-attention partials, single pass with online softmax.
// Block (j,h) handles half-segment h (32 frames) of segment j; queries
// j-1, j, j+1. Lane owns dims [8l,8l+8) for BOTH the score dot and the
// weighted-sum accumulation, so mem is read exactly once (no phase-C re-read).
// Grid 1024 x 256.
// ---------------------------------------------------------------------------
__global__ __launch_bounds__(256) void k_ca_partial(
    const float* __restrict__ tgt, const float* __restrict__ qpos,
    const float* __restrict__ mem, const float* __restrict__ pos,
    float* __restrict__ part_acc, float* __restrict__ part_ms) {
  const int j = blockIdx.x >> 1;
  const int h = blockIdx.x & 1;
  const int tid = threadIdx.x;
  const int wave = tid >> 6, lane = tid & 63;
  const int d0 = lane * 8;

  __shared__ float wacc[4][3][DIM];
  __shared__ float wms[4][3][2];

  float qf[3][8];
#pragma unroll
  for (int c = 0; c < 3; ++c) {
    const int qi = j - 1 + c;
    if ((unsigned)qi < (unsigned)S_Q) {
      const float4* tp = (const float4*)(tgt + (size_t)qi * DIM + d0);
      const float4* qp = (const float4*)(qpos + (size_t)qi * DIM + d0);
      float4 t0 = tp[0], t1 = tp[1], q0 = qp[0], q1 = qp[1];
      qf[c][0] = t0.x + q0.x; qf[c][1] = t0.y + q0.y;
      qf[c][2] = t0.z + q0.z; qf[c][3] = t0.w + q0.w;
      qf[c][4] = t1.x + q1.x; qf[c][5] = t1.y + q1.y;
      qf[c][6] = t1.z + q1.z; qf[c][7] = t1.w + q1.w;
    } else {
#pragma unroll
      for (int e = 0; e < 8; ++e) qf[c][e] = 0.f;
    }
  }

  float m[3] = {-1e30f, -1e30f, -1e30f};
  float ssum[3] = {0.f, 0.f, 0.f};
  float acc[3][8];
#pragma unroll
  for (int c = 0; c < 3; ++c)
#pragma unroll
    for (int e = 0; e < 8; ++e) acc[c][e] = 0.f;

  const size_t fbase = (size_t)j * 64 + h * 32 + wave * 8;
#pragma unroll 2
  for (int it = 0; it < 8; ++it) {
    const size_t f = fbase + it;
    const float4* mp = (const float4*)(mem + f * DIM + d0);
    const float4* pp = (const float4*)(pos + f * DIM + d0);
    float4 m0 = mp[0], m1 = mp[1], p0 = pp[0], p1 = pp[1];
    float mv[8] = {m0.x, m0.y, m0.z, m0.w, m1.x, m1.y, m1.z, m1.w};
    float kk[8] = {m0.x + p0.x, m0.y + p0.y, m0.z + p0.z, m0.w + p0.w,
                   m1.x + p1.x, m1.y + p1.y, m1.z + p1.z, m1.w + p1.w};
    float s0 = 0.f, s1 = 0.f, s2 = 0.f;
#pragma unroll
    for (int e = 0; e < 8; ++e) {
      s0 += qf[0][e] * kk[e];
      s1 += qf[1][e] * kk[e];
      s2 += qf[2][e] * kk[e];
    }
#pragma unroll
    for (int off = 32; off > 0; off >>= 1) {
      s0 += __shfl_xor(s0, off);
      s1 += __shfl_xor(s1, off);
      s2 += __shfl_xor(s2, off);
    }
    const float sc3[3] = {s0 * SCALE_F, s1 * SCALE_F, s2 * SCALE_F};
#pragma unroll
    for (int c = 0; c < 3; ++c) {
      const float s = sc3[c];
      if (s > m[c]) {  // wave-uniform branch (s identical across lanes)
        const float fct = __expf(m[c] - s);
        ssum[c] = ssum[c] * fct + 1.f;
#pragma unroll
        for (int e = 0; e < 8; ++e) acc[c][e] = acc[c][e] * fct + mv[e];
        m[c] = s;
      } else {
        const float ee = __expf(s - m[c]);
        ssum[c] += ee;
#pragma unroll
        for (int e = 0; e < 8; ++e) acc[c][e] += ee * mv[e];
      }
    }
  }

  // per-wave partials -> LDS
#pragma unroll
  for (int c = 0; c < 3; ++c) {
    *(float4*)(&wacc[wave][c][d0]) =
        make_float4(acc[c][0], acc[c][1], acc[c][2], acc[c][3]);
    *(float4*)(&wacc[wave][c][d0 + 4]) =
        make_float4(acc[c][4], acc[c][5], acc[c][6], acc[c][7]);
    if (lane == 0) { wms[wave][c][0] = m[c]; wms[wave][c][1] = ssum[c]; }
  }
  __syncthreads();

  // cross-wave combine, write block partial (slot = c*2 + h)
  const int d = tid * 2;
#pragma unroll
  for (int c = 0; c < 3; ++c) {
    const int qi = j - 1 + c;
    if ((unsigned)qi >= (unsigned)S_Q) continue;
    float M = wms[0][c][0];
#pragma unroll
    for (int w = 1; w < 4; ++w) M = fmaxf(M, wms[w][c][0]);
    float S = 0.f, ax = 0.f, ay = 0.f;
#pragma unroll
    for (int w = 0; w < 4; ++w) {
      const float wgt = __expf(wms[w][c][0] - M);
      S += wgt * wms[w][c][1];
      const float2 a = *(const float2*)(&wacc[w][c][d]);
      ax += wgt * a.x;
      ay += wgt * a.y;
    }
    const size_t slot = (size_t)qi * 6 + c * 2 + h;
    *(float2*)(part_acc + slot * DIM + d) = make_float2(ax, ay);
    if (tid == 0) {
      part_ms[slot * 2 + 0] = M;
      part_ms[slot * 2 + 1] = S;
    }
  }
}

// ---------------------------------------------------------------------------
// K2: combine the 6 partials per query, finish softmax, apply ReLU.
// Query i: slots {0,1} from segment i+1 (valid i<511), {2,3} from segment i,
// {4,5} from segment i-1 (valid i>0).
// ---------------------------------------------------------------------------
__global__ __launch_bounds__(256) void k_ca_combine(
    const float* __restrict__ part_acc, const float* __restrict__ part_ms,
    float* __restrict__ t2r) {
  const int i = blockIdx.x;
  const int tid = threadIdx.x;
  const bool valid[3] = {i < S_Q - 1, true, i > 0};
  float ms[6], ss[6];
  float M = -1e30f;
#pragma unroll
  for (int k = 0; k < 6; ++k) {
    if (valid[k >> 1]) {
      ms[k] = part_ms[((size_t)i * 6 + k) * 2 + 0];
      ss[k] = part_ms[((size_t)i * 6 + k) * 2 + 1];
      M = fmaxf(M, ms[k]);
    } else {
      ms[k] = -1e30f;
      ss[k] = 0.f;
    }
  }
  float wgt[6];
  float den = 0.f;
#pragma unroll
  for (int k = 0; k < 6; ++k) {
    wgt[k] = valid[k >> 1] ? __expf(ms[k] - M) : 0.f;
    den += wgt[k] * ss[k];
  }
  const float inv = 1.f / den;
  const int d = tid * 2;
  float ox = 0.f, oy = 0.f;
#pragma unroll
  for (int k = 0; k < 6; ++k) {
    if (valid[k >> 1]) {
      const float2 a = *(const float2*)(part_acc + ((size_t)i * 6 + k) * DIM + d);
      ox += wgt[k] * a.x;
      oy += wgt[k] * a.y;
    }
  }
  ox = fmaxf(ox * inv, 0.f);
  oy = fmaxf(oy * inv, 0.f);
  *(float2*)(t2r + (size_t)i * DIM + d) = make_float2(ox, oy);
}

// ---------------------------------------------------------------------------
// bf16 MFMA GEMM: C[i][o] = sum_k A[i][k]*W[o][k] + bias[o], optional ReLU.
// 32x32 tile per block (4 waves, one 16x16 quadrant each), grid 16x16.
// fp32 inputs converted RTNE->bf16 during LDS staging; fp32 accumulate.
// LDS row stride 72 shorts (144 B) keeps b128 frag reads ~conflict-free.
// ---------------------------------------------------------------------------
template <bool RELU>
__global__ __launch_bounds__(256) void k_gemm512(
    const float* __restrict__ A, const float* __restrict__ W,
    const float* __restrict__ bias, float* __restrict__ C) {
  __shared__ short As[32 * 72];
  __shared__ short Ws[32 * 72];
  const int tid = threadIdx.x;
  const int bx = blockIdx.x, by = blockIdx.y;
  const int wave = tid >> 6, lane = tid & 63;
  const int srow = tid >> 3, sk = (tid & 7) * 4;
  const float* Ag = A + (size_t)(by * 32 + srow) * DIM + sk;
  const float* Wg = W + (size_t)(bx * 32 + srow) * DIM + sk;
  const int r0 = (wave >> 1) * 16, c0 = (wave & 1) * 16;
  const int frow = lane & 15, fk = (lane >> 4) * 8;
  floatx4 acc = {0.f, 0.f, 0.f, 0.f};
  for (int kc = 0; kc < DIM; kc += 32) {
    const float4 av = *(const float4*)(Ag + kc);
    const float4 wv = *(const float4*)(Wg + kc);
    __syncthreads();
    short* ap = &As[srow * 72 + sk];
    ap[0] = (short)f2bf(av.x); ap[1] = (short)f2bf(av.y);
    ap[2] = (short)f2bf(av.z); ap[3] = (short)f2bf(av.w);
    short* wp = &Ws[srow * 72 + sk];
    wp[0] = (short)f2bf(wv.x); wp[1] = (short)f2bf(wv.y);
    wp[2] = (short)f2bf(wv.z); wp[3] = (short)f2bf(wv.w);
    __syncthreads();
    const short8 af = *(const short8*)(&As[(r0 + frow) * 72 + fk]);
    const short8 wf = *(const short8*)(&Ws[(c0 + frow) * 72 + fk]);
    acc = __builtin_amdgcn_mfma_f32_16x16x32_bf16(af, wf, acc, 0, 0, 0);
  }
  const int col = bx * 32 + c0 + (lane & 15);
  const int rowb = by * 32 + r0 + (lane >> 4) * 4;
  const float b = bias[col];
#pragma unroll
  for (int r = 0; r < 4; ++r) {
    float val = acc[r] + b;
    if (RELU) val = fmaxf(val, 0.f);
    C[(size_t)(rowb + r) * DIM + col] = val;
  }
}

// ---------------------------------------------------------------------------
// Residual add + LayerNorm. One wave per 512-float row, 4 rows per block.
// ---------------------------------------------------------------------------
__global__ __launch_bounds__(256) void k_addln(
    const float* __restrict__ X, const float* __restrict__ R,
    const float* __restrict__ g, const float* __restrict__ b,
    float* __restrict__ out) {
  const int row = blockIdx.x * 4 + (threadIdx.x >> 6);
  const int lane = threadIdx.x & 63;
  const int d = lane * 8;
  const float4* xp = (const float4*)(X + (size_t)row * DIM + d);
  const float4* rp = (const float4*)(R + (size_t)row * DIM + d);
  float4 x0 = xp[0], x1 = xp[1], r0 = rp[0], r1 = rp[1];
  float v[8] = {x0.x + r0.x, x0.y + r0.y, x0.z + r0.z, x0.w + r0.w,
                x1.x + r1.x, x1.y + r1.y, x1.z + r1.z, x1.w + r1.w};
  float s = 0.f, sq = 0.f;
#pragma unroll
  for (int e = 0; e < 8; ++e) { s += v[e]; sq += v[e] * v[e]; }
  s = wave_reduce_sum(s);
  sq = wave_reduce_sum(sq);
  const float mean = s * (1.f / DIM);
  const float var = sq * (1.f / DIM) - mean * mean;
  const float rstd = rsqrtf(var + 1e-5f);
  const float4* gp = (const float4*)(g + d);
  const float4* bp = (const float4*)(b + d);
  float4 g0 = gp[0], g1 = gp[1], bb0 = bp[0], bb1 = bp[1];
  float4 o0, o1;
  o0.x = (v[0] - mean) * rstd * g0.x + bb0.x;
  o0.y = (v[1] - mean) * rstd * g0.y + bb0.y;
  o0.z = (v[2] - mean) * rstd * g0.z + bb0.z;
  o0.w = (v[3] - mean) * rstd * g0.w + bb0.w;
  o1.x = (v[4] - mean) * rstd * g1.x + bb1.x;
  o1.y = (v[5] - mean) * rstd * g1.y + bb1.y;
  o1.z = (v[6] - mean) * rstd * g1.z + bb1.z;
  o1.w = (v[7] - mean) * rstd * g1.w + bb1.w;
  *(float4*)(out + (size_t)row * DIM + d) = o0;
  *(float4*)(out + (size_t)row * DIM + d + 4) = o1;
}

// ---------------------------------------------------------------------------
// Banded self-attention (+/-4) + ReLU, one block per query.
// ---------------------------------------------------------------------------
__global__ __launch_bounds__(256) void k_sa_attn(const float* __restrict__ X,
                                                 float* __restrict__ outr) {
  const int i = blockIdx.x;
  const int tid = threadIdx.x;
  const int wave = tid >> 6, lane = tid & 63;
  const int jlo = (i - 4 > 0) ? i - 4 : 0;
  const int jhi = (i + 4 < S_Q - 1) ? i + 4 : S_Q - 1;
  const int n = jhi - jlo + 1;
  __shared__ float sc[9];
  const int d0 = lane * 8;
  const float4* qp = (const float4*)(X + (size_t)i * DIM + d0);
  float4 q0 = qp[0], q1 = qp[1];
  for (int idx = wave; idx < n; idx += 4) {
    const float4* kp = (const float4*)(X + (size_t)(jlo + idx) * DIM + d0);
    float4 k0 = kp[0], k1 = kp[1];
    float s = q0.x * k0.x + q0.y * k0.y + q0.z * k0.z + q0.w * k0.w +
              q1.x * k1.x + q1.y * k1.y + q1.z * k1.z + q1.w * k1.w;
    s = wave_reduce_sum(s);
    if (lane == 0) sc[idx] = s * SCALE_F;
  }
  __syncthreads();
  float m = -3.0e38f;
#pragma unroll
  for (int k = 0; k < 9; ++k)
    if (k < n) m = fmaxf(m, sc[k]);
  float p[9];
  float den = 0.f;
#pragma unroll
  for (int k = 0; k < 9; ++k) {
    p[k] = (k < n) ? __expf(sc[k] - m) : 0.f;
    den += p[k];
  }
  const float inv = 1.f / den;
  const int d = tid * 2;
  float ox = 0.f, oy = 0.f;
#pragma unroll
  for (int k = 0; k < 9; ++k) {
    if (k < n) {
      float2 xv = *(const float2*)(X + (size_t)(jlo + k) * DIM + d);
      ox += p[k] * xv.x;
      oy += p[k] * xv.y;
    }
  }
  ox = fmaxf(ox * inv, 0.f);
  oy = fmaxf(oy * inv, 0.f);
  *(float2*)(outr + (size_t)i * DIM + d) = make_float2(ox, oy);
}

// ---------------------------------------------------------------------------
extern "C" void kernel_launch(void* const* d_in, const int* in_sizes, int n_in,
                              void* d_out, int out_size, void* d_ws, size_t ws_size,
                              hipStream_t stream) {
  const float* tgt       = (const float*)d_in[0];
  const float* memory    = (const float*)d_in[1];
  const float* pos       = (const float*)d_in[2];
  const float* qpos      = (const float*)d_in[3];
  // d_in[4] action_idx: analytically t/64, unused
  const float* ca_t2l_w  = (const float*)d_in[5];
  const float* ca_t2l_b  = (const float*)d_in[6];
  const float* ca_l1_w   = (const float*)d_in[7];
  const float* ca_l1_b   = (const float*)d_in[8];
  const float* ca_l2_w   = (const float*)d_in[9];
  const float* ca_l2_b   = (const float*)d_in[10];
  const float* ca_n2_g   = (const float*)d_in[11];
  const float* ca_n2_b   = (const float*)d_in[12];
  const float* ca_n3_g   = (const float*)d_in[13];
  const float* ca_n3_b   = (const float*)d_in[14];
  const float* sa_conv_w = (const float*)d_in[15];
  const float* sa_conv_b = (const float*)d_in[16];
  const float* sa_l1_w   = (const float*)d_in[17];
  const float* sa_l1_b   = (const float*)d_in[18];
  const float* sa_l2_w   = (const float*)d_in[19];
  const float* sa_l2_b   = (const float*)d_in[20];
  const float* sa_n1_g   = (const float*)d_in[21];
  const float* sa_n1_b   = (const float*)d_in[22];
  const float* sa_n2_g   = (const float*)d_in[23];
  const float* sa_n2_b   = (const float*)d_in[24];
  float* out = (float*)d_out;
  float* ws = (float*)d_ws;

  // workspace layout (floats). part region: 512*6*512 + 512*6*2 = 1579008.
  // bufA lives beyond it; buf1..buf3 alias the dead part region after combine.
  // Peak: 1841152 floats = 7.37 MB.
  float* part_acc = ws;                // [512][6][512]
  float* part_ms  = ws + 1572864;      // [512][6][2]
  float* bufA     = ws + 1579008;      // 262144 (never aliased)
  float* buf1     = ws;                // aliases dead part_acc
  float* buf2     = ws + 262144;
  float* buf3     = ws + 524288;

  const dim3 gg(16, 16, 1);

  // ---- cross attention ----
  k_ca_partial<<<1024, 256, 0, stream>>>(tgt, qpos, memory, pos, part_acc, part_ms);
  k_ca_combine<<<512, 256, 0, stream>>>(part_acc, part_ms, bufA);       // relu(attn@mem)
  k_gemm512<false><<<gg, 256, 0, stream>>>(bufA, ca_t2l_w, ca_t2l_b, buf1);
  k_addln<<<128, 256, 0, stream>>>(buf1, tgt, ca_n2_g, ca_n2_b, buf2);  // x
  k_gemm512<true><<<gg, 256, 0, stream>>>(buf2, ca_l1_w, ca_l1_b, bufA);   // h
  k_gemm512<false><<<gg, 256, 0, stream>>>(bufA, ca_l2_w, ca_l2_b, buf1);
  k_addln<<<128, 256, 0, stream>>>(buf1, buf2, ca_n3_g, ca_n3_b, buf3); // x2
  // ---- self attention ----
  k_sa_attn<<<512, 256, 0, stream>>>(buf3, bufA);                       // relu(attn@src)
  k_gemm512<false><<<gg, 256, 0, stream>>>(bufA, sa_conv_w, sa_conv_b, buf1);
  k_addln<<<128, 256, 0, stream>>>(buf1, buf3, sa_n1_g, sa_n1_b, buf2); // y1
  k_gemm512<true><<<gg, 256, 0, stream>>>(buf2, sa_l1_w, sa_l1_b, bufA);   // h2
  k_gemm512<false><<<gg, 256, 0, stream>>>(bufA, sa_l2_w, sa_l2_b, buf1);
  k_addln<<<128, 256, 0, stream>>>(buf1, buf2, sa_n2_g, sa_n2_b, out);
}

// Round 3
// 292.134 us; speedup vs baseline: 1.2207x; 1.0272x over previous
//
#include <hip/hip_runtime.h>

#define S_Q 512
#define DIM 512
#define SCALE_F 0.04419417382415922f  // 1/sqrt(512)
#define LDS_W 520                     // LDS row stride in shorts (breaks pow2 aliasing)

typedef short short8 __attribute__((ext_vector_type(8)));
typedef float floatx4 __attribute__((ext_vector_type(4)));

__device__ __forceinline__ float wave_sum(float v) {
#pragma unroll
  for (int o = 32; o > 0; o >>= 1) v += __shfl_xor(v, o);
  return v;
}
__device__ __forceinline__ unsigned short f2bf(float f) {
  unsigned u = __float_as_uint(f);
  return (unsigned short)((u + 0x7FFFu + ((u >> 16) & 1u)) >> 16);
}
__device__ __forceinline__ float bf2f(short s) {
  return __uint_as_float(((unsigned)(unsigned short)s) << 16);
}

// ---------------------------------------------------------------------------
// K1: cross-attention partials. One block per 64-frame segment j; queries
// j-1,j,j+1. Wave handles 16 frames in 4 batches of 4: all 16 float4 loads of
// a batch are issued before any dependent compute (BW-bound structure).
// part_acc written bf16.
// ---------------------------------------------------------------------------
__global__ __launch_bounds__(256) void k_ca_partial(
    const float* __restrict__ tgt, const float* __restrict__ qpos,
    const float* __restrict__ mem, const float* __restrict__ pos,
    unsigned short* __restrict__ part_acc, float* __restrict__ part_ms) {
  const int j = blockIdx.x;
  const int tid = threadIdx.x;
  const int wave = tid >> 6, lane = tid & 63;
  const int d0 = lane * 8;
  __shared__ float wacc[4][3][DIM];
  __shared__ float wms[4][3][2];

  float qf[3][8];
#pragma unroll
  for (int c = 0; c < 3; ++c) {
    const int qi = j - 1 + c;
    if ((unsigned)qi < (unsigned)S_Q) {
      float4 t0 = *(const float4*)(tgt + (size_t)qi * DIM + d0);
      float4 t1 = *(const float4*)(tgt + (size_t)qi * DIM + d0 + 4);
      float4 q0 = *(const float4*)(qpos + (size_t)qi * DIM + d0);
      float4 q1 = *(const float4*)(qpos + (size_t)qi * DIM + d0 + 4);
      qf[c][0] = t0.x + q0.x; qf[c][1] = t0.y + q0.y;
      qf[c][2] = t0.z + q0.z; qf[c][3] = t0.w + q0.w;
      qf[c][4] = t1.x + q1.x; qf[c][5] = t1.y + q1.y;
      qf[c][6] = t1.z + q1.z; qf[c][7] = t1.w + q1.w;
    } else {
#pragma unroll
      for (int e = 0; e < 8; ++e) qf[c][e] = 0.f;
    }
  }

  float m[3] = {-1e30f, -1e30f, -1e30f};
  float ssum[3] = {0.f, 0.f, 0.f};
  float acc[3][8];
#pragma unroll
  for (int c = 0; c < 3; ++c)
#pragma unroll
    for (int e = 0; e < 8; ++e) acc[c][e] = 0.f;

  const float* mbase = mem + ((size_t)j * 64 + wave * 16) * DIM + d0;
  const float* pbase = pos + ((size_t)j * 64 + wave * 16) * DIM + d0;

  for (int b = 0; b < 4; ++b) {
    float mv[4][8], kk[4][8];
#pragma unroll
    for (int f = 0; f < 4; ++f) {
      const float* mp = mbase + (size_t)(b * 4 + f) * DIM;
      const float* pp = pbase + (size_t)(b * 4 + f) * DIM;
      float4 a = *(const float4*)mp;
      float4 bb = *(const float4*)(mp + 4);
      float4 c4 = *(const float4*)pp;
      float4 dd = *(const float4*)(pp + 4);
      mv[f][0] = a.x;  mv[f][1] = a.y;  mv[f][2] = a.z;  mv[f][3] = a.w;
      mv[f][4] = bb.x; mv[f][5] = bb.y; mv[f][6] = bb.z; mv[f][7] = bb.w;
      kk[f][0] = a.x + c4.x;  kk[f][1] = a.y + c4.y;
      kk[f][2] = a.z + c4.z;  kk[f][3] = a.w + c4.w;
      kk[f][4] = bb.x + dd.x; kk[f][5] = bb.y + dd.y;
      kk[f][6] = bb.z + dd.z; kk[f][7] = bb.w + dd.w;
    }
    float dots[3][4];
#pragma unroll
    for (int f = 0; f < 4; ++f) {
      float s0 = 0.f, s1 = 0.f, s2 = 0.f;
#pragma unroll
      for (int e = 0; e < 8; ++e) {
        s0 += qf[0][e] * kk[f][e];
        s1 += qf[1][e] * kk[f][e];
        s2 += qf[2][e] * kk[f][e];
      }
      dots[0][f] = s0; dots[1][f] = s1; dots[2][f] = s2;
    }
    // all 12 butterflies independent -> pipeline
#pragma unroll
    for (int o = 32; o > 0; o >>= 1)
#pragma unroll
      for (int c = 0; c < 3; ++c)
#pragma unroll
        for (int f = 0; f < 4; ++f) dots[c][f] += __shfl_xor(dots[c][f], o);
#pragma unroll
    for (int c = 0; c < 3; ++c) {
      float s[4];
#pragma unroll
      for (int f = 0; f < 4; ++f) s[f] = dots[c][f] * SCALE_F;
      const float bm = fmaxf(fmaxf(s[0], s[1]), fmaxf(s[2], s[3]));
      const float nm = fmaxf(m[c], bm);
      const float fct = __expf(m[c] - nm);
      m[c] = nm;
      ssum[c] *= fct;
#pragma unroll
      for (int e = 0; e < 8; ++e) acc[c][e] *= fct;
#pragma unroll
      for (int f = 0; f < 4; ++f) {
        const float w = __expf(s[f] - nm);
        ssum[c] += w;
#pragma unroll
        for (int e = 0; e < 8; ++e) acc[c][e] += w * mv[f][e];
      }
    }
  }

  // per-wave partials -> LDS
#pragma unroll
  for (int c = 0; c < 3; ++c) {
    *(float4*)(&wacc[wave][c][d0]) =
        make_float4(acc[c][0], acc[c][1], acc[c][2], acc[c][3]);
    *(float4*)(&wacc[wave][c][d0 + 4]) =
        make_float4(acc[c][4], acc[c][5], acc[c][6], acc[c][7]);
    if (lane == 0) { wms[wave][c][0] = m[c]; wms[wave][c][1] = ssum[c]; }
  }
  __syncthreads();

  const int d = tid * 2;
#pragma unroll
  for (int c = 0; c < 3; ++c) {
    const int qi = j - 1 + c;
    if ((unsigned)qi >= (unsigned)S_Q) continue;
    float M = wms[0][c][0];
#pragma unroll
    for (int w = 1; w < 4; ++w) M = fmaxf(M, wms[w][c][0]);
    float S = 0.f, ax = 0.f, ay = 0.f;
#pragma unroll
    for (int w = 0; w < 4; ++w) {
      const float wg = __expf(wms[w][c][0] - M);
      S += wg * wms[w][c][1];
      const float2 a = *(const float2*)(&wacc[w][c][d]);
      ax += wg * a.x;
      ay += wg * a.y;
    }
    const size_t slot = (size_t)qi * 3 + c;
    unsigned short* dst = part_acc + slot * DIM + d;
    dst[0] = f2bf(ax);
    dst[1] = f2bf(ay);
    if (tid == 0) {
      part_ms[slot * 2 + 0] = M;
      part_ms[slot * 2 + 1] = S;
    }
  }
}

// ---------------------------------------------------------------------------
// Shared GEMM pieces. Tile: 32(M) x 32(N), K=512 fully LDS-resident (bf16).
// 4 waves, one 16x16 quadrant each; 16 MFMAs back-to-back after one barrier.
// ---------------------------------------------------------------------------
__device__ __forceinline__ void stage_tile(const float* __restrict__ G,
                                           short* __restrict__ Ls,
                                           int rowblk, int tid) {
  const int row = tid >> 3;
  const int c0 = (tid & 7) * 64;
  const float* src = G + (size_t)(rowblk * 32 + row) * DIM + c0;
  short* dst = &Ls[row * LDS_W + c0];
#pragma unroll
  for (int u = 0; u < 8; ++u) {
    float4 a = *(const float4*)(src + u * 8);
    float4 b = *(const float4*)(src + u * 8 + 4);
    short8 s;
    s[0] = (short)f2bf(a.x); s[1] = (short)f2bf(a.y);
    s[2] = (short)f2bf(a.z); s[3] = (short)f2bf(a.w);
    s[4] = (short)f2bf(b.x); s[5] = (short)f2bf(b.y);
    s[6] = (short)f2bf(b.z); s[7] = (short)f2bf(b.w);
    *(short8*)(dst + u * 8) = s;
  }
}

template <bool RELU>
__device__ __forceinline__ void gemm_core(const short* __restrict__ As,
                                          const short* __restrict__ Ws,
                                          const float* __restrict__ bias,
                                          float* __restrict__ C, int bx, int by,
                                          int wave, int lane) {
  const int r0 = (wave >> 1) * 16, c0 = (wave & 1) * 16;
  const int frow = lane & 15, fk = (lane >> 4) * 8;
  const short* ap = &As[(r0 + frow) * LDS_W + fk];
  const short* wp = &Ws[(c0 + frow) * LDS_W + fk];
  floatx4 acc = {0.f, 0.f, 0.f, 0.f};
#pragma unroll
  for (int kc = 0; kc < 16; ++kc) {
    const short8 af = *(const short8*)(ap + kc * 32);
    const short8 wf = *(const short8*)(wp + kc * 32);
    acc = __builtin_amdgcn_mfma_f32_16x16x32_bf16(af, wf, acc, 0, 0, 0);
  }
  const int col = bx * 32 + c0 + frow;
  const int rowb = by * 32 + r0 + (lane >> 4) * 4;
  const float b = bias[col];
#pragma unroll
  for (int r = 0; r < 4; ++r) {
    float v = acc[r] + b;
    if (RELU) v = fmaxf(v, 0.f);
    C[(size_t)(rowb + r) * DIM + col] = v;
  }
}

// LN prologue: As[r] = bf16(LN(X[row]+R[row])*g+b) for 32 rows; optionally
// write fp32 LN result to x_out (bx==0 blocks).
__device__ __forceinline__ void ln_prologue(const float* __restrict__ X,
                                            const float* __restrict__ R,
                                            const float* __restrict__ g,
                                            const float* __restrict__ b,
                                            short* __restrict__ As, int by,
                                            float* x_out, int wave, int lane) {
  const int d0 = lane * 8;
  float gg[8], bb[8];
  {
    float4 g0 = *(const float4*)(g + d0);
    float4 g1 = *(const float4*)(g + d0 + 4);
    float4 b0 = *(const float4*)(b + d0);
    float4 b1 = *(const float4*)(b + d0 + 4);
    gg[0] = g0.x; gg[1] = g0.y; gg[2] = g0.z; gg[3] = g0.w;
    gg[4] = g1.x; gg[5] = g1.y; gg[6] = g1.z; gg[7] = g1.w;
    bb[0] = b0.x; bb[1] = b0.y; bb[2] = b0.z; bb[3] = b0.w;
    bb[4] = b1.x; bb[5] = b1.y; bb[6] = b1.z; bb[7] = b1.w;
  }
  for (int r = wave; r < 32; r += 4) {
    const int grow = by * 32 + r;
    const float* xp = X + (size_t)grow * DIM + d0;
    const float* rp = R + (size_t)grow * DIM + d0;
    float4 x0 = *(const float4*)xp;
    float4 x1 = *(const float4*)(xp + 4);
    float4 r0 = *(const float4*)rp;
    float4 r1 = *(const float4*)(rp + 4);
    float v[8] = {x0.x + r0.x, x0.y + r0.y, x0.z + r0.z, x0.w + r0.w,
                  x1.x + r1.x, x1.y + r1.y, x1.z + r1.z, x1.w + r1.w};
    float s = 0.f, sq = 0.f;
#pragma unroll
    for (int e = 0; e < 8; ++e) { s += v[e]; sq += v[e] * v[e]; }
#pragma unroll
    for (int o = 32; o > 0; o >>= 1) {
      s += __shfl_xor(s, o);
      sq += __shfl_xor(sq, o);
    }
    const float mean = s * (1.f / DIM);
    const float var = sq * (1.f / DIM) - mean * mean;
    const float rstd = rsqrtf(var + 1e-5f);
    float o8[8];
    short8 sv;
#pragma unroll
    for (int e = 0; e < 8; ++e) {
      o8[e] = (v[e] - mean) * rstd * gg[e] + bb[e];
      sv[e] = (short)f2bf(o8[e]);
    }
    *(short8*)(&As[r * LDS_W + d0]) = sv;
    if (x_out) {
      *(float4*)(x_out + (size_t)grow * DIM + d0) =
          make_float4(o8[0], o8[1], o8[2], o8[3]);
      *(float4*)(x_out + (size_t)grow * DIM + d0 + 4) =
          make_float4(o8[4], o8[5], o8[6], o8[7]);
    }
  }
}

// ---------------------------------------------------------------------------
// G1: combine partials (finish softmax) + ReLU  ->  GEMM with ca_t2l_w.
// ---------------------------------------------------------------------------
__global__ __launch_bounds__(256) void k_g1(
    const unsigned short* __restrict__ part_acc,
    const float* __restrict__ part_ms, const float* __restrict__ W,
    const float* __restrict__ bias, float* __restrict__ C) {
  __shared__ short As[32 * LDS_W];
  __shared__ short Ws[32 * LDS_W];
  const int tid = threadIdx.x;
  const int bx = blockIdx.x, by = blockIdx.y;
  const int wave = tid >> 6, lane = tid & 63;
  const int d0 = lane * 8;
  for (int r = wave; r < 32; r += 4) {
    const int i = by * 32 + r;
    const bool valid[3] = {i < S_Q - 1, true, i > 0};
    float mm[3], ss[3], M = -1e30f;
#pragma unroll
    for (int c = 0; c < 3; ++c) {
      if (valid[c]) {
        mm[c] = part_ms[((size_t)i * 3 + c) * 2 + 0];
        ss[c] = part_ms[((size_t)i * 3 + c) * 2 + 1];
        M = fmaxf(M, mm[c]);
      } else {
        mm[c] = -1e30f;
        ss[c] = 0.f;
      }
    }
    float den = 0.f, wg[3];
#pragma unroll
    for (int c = 0; c < 3; ++c) {
      wg[c] = valid[c] ? __expf(mm[c] - M) : 0.f;
      den += wg[c] * ss[c];
    }
    const float inv = 1.f / den;
    float o[8] = {0.f, 0.f, 0.f, 0.f, 0.f, 0.f, 0.f, 0.f};
#pragma unroll
    for (int c = 0; c < 3; ++c) {
      if (valid[c]) {
        const short8 pa =
            *(const short8*)(part_acc + ((size_t)i * 3 + c) * DIM + d0);
#pragma unroll
        for (int e = 0; e < 8; ++e) o[e] += wg[c] * bf2f(pa[e]);
      }
    }
    short8 sv;
#pragma unroll
    for (int e = 0; e < 8; ++e) sv[e] = (short)f2bf(fmaxf(o[e] * inv, 0.f));
    *(short8*)(&As[r * LDS_W + d0]) = sv;
  }
  stage_tile(W, Ws, bx, tid);
  __syncthreads();
  gemm_core<false>(As, Ws, bias, C, bx, by, wave, lane);
}

// ---------------------------------------------------------------------------
// G2/G5: LN(X+R) prologue (write x_out when bx==0) -> GEMM (ReLU epilogue).
// ---------------------------------------------------------------------------
__global__ __launch_bounds__(256) void k_gln(
    const float* __restrict__ X, const float* __restrict__ R,
    const float* __restrict__ g, const float* __restrict__ b,
    const float* __restrict__ W, const float* __restrict__ bias,
    float* __restrict__ C, float* __restrict__ x_out) {
  __shared__ short As[32 * LDS_W];
  __shared__ short Ws[32 * LDS_W];
  const int tid = threadIdx.x;
  const int bx = blockIdx.x, by = blockIdx.y;
  const int wave = tid >> 6, lane = tid & 63;
  ln_prologue(X, R, g, b, As, by, (bx == 0) ? x_out : nullptr, wave, lane);
  stage_tile(W, Ws, bx, tid);
  __syncthreads();
  gemm_core<true>(As, Ws, bias, C, bx, by, wave, lane);
}

// ---------------------------------------------------------------------------
// G3/G6: plain GEMM (A fp32 global), no relu.
// ---------------------------------------------------------------------------
__global__ __launch_bounds__(256) void k_gplain(
    const float* __restrict__ A, const float* __restrict__ W,
    const float* __restrict__ bias, float* __restrict__ C) {
  __shared__ short As[32 * LDS_W];
  __shared__ short Ws[32 * LDS_W];
  const int tid = threadIdx.x;
  const int bx = blockIdx.x, by = blockIdx.y;
  const int wave = tid >> 6, lane = tid & 63;
  stage_tile(A, As, by, tid);
  stage_tile(W, Ws, bx, tid);
  __syncthreads();
  gemm_core<false>(As, Ws, bias, C, bx, by, wave, lane);
}

// ---------------------------------------------------------------------------
// G4: x2 = LN(x+f) on a 40-row window (write own rows when bx==0), banded
// self-attention (+/-4) + ReLU -> GEMM with sa_conv_w.
// ---------------------------------------------------------------------------
__global__ __launch_bounds__(256) void k_g4(
    const float* __restrict__ X, const float* __restrict__ R,
    const float* __restrict__ g, const float* __restrict__ b,
    const float* __restrict__ W, const float* __restrict__ bias,
    float* __restrict__ C, float* __restrict__ x2_out) {
  __shared__ short Xw[40 * LDS_W];
  __shared__ short As[32 * LDS_W];
  __shared__ short Ws[32 * LDS_W];
  const int tid = threadIdx.x;
  const int bx = blockIdx.x, by = blockIdx.y;
  const int wave = tid >> 6, lane = tid & 63;
  const int d0 = lane * 8;
  const int wlo = (by * 32 - 4 > 0) ? by * 32 - 4 : 0;
  const int whi = (by * 32 + 35 < S_Q - 1) ? by * 32 + 35 : S_Q - 1;
  const int nw = whi - wlo + 1;

  // LN window fill
  {
    float gg[8], bb[8];
    float4 g0 = *(const float4*)(g + d0);
    float4 g1 = *(const float4*)(g + d0 + 4);
    float4 b0 = *(const float4*)(b + d0);
    float4 b1 = *(const float4*)(b + d0 + 4);
    gg[0] = g0.x; gg[1] = g0.y; gg[2] = g0.z; gg[3] = g0.w;
    gg[4] = g1.x; gg[5] = g1.y; gg[6] = g1.z; gg[7] = g1.w;
    bb[0] = b0.x; bb[1] = b0.y; bb[2] = b0.z; bb[3] = b0.w;
    bb[4] = b1.x; bb[5] = b1.y; bb[6] = b1.z; bb[7] = b1.w;
    for (int r = wave; r < nw; r += 4) {
      const int grow = wlo + r;
      const float* xp = X + (size_t)grow * DIM + d0;
      const float* rp = R + (size_t)grow * DIM + d0;
      float4 x0 = *(const float4*)xp;
      float4 x1 = *(const float4*)(xp + 4);
      float4 r0 = *(const float4*)rp;
      float4 r1 = *(const float4*)(rp + 4);
      float v[8] = {x0.x + r0.x, x0.y + r0.y, x0.z + r0.z, x0.w + r0.w,
                    x1.x + r1.x, x1.y + r1.y, x1.z + r1.z, x1.w + r1.w};
      float s = 0.f, sq = 0.f;
#pragma unroll
      for (int e = 0; e < 8; ++e) { s += v[e]; sq += v[e] * v[e]; }
#pragma unroll
      for (int o = 32; o > 0; o >>= 1) {
        s += __shfl_xor(s, o);
        sq += __shfl_xor(sq, o);
      }
      const float mean = s * (1.f / DIM);
      const float var = sq * (1.f / DIM) - mean * mean;
      const float rstd = rsqrtf(var + 1e-5f);
      float o8[8];
      short8 sv;
#pragma unroll
      for (int e = 0; e < 8; ++e) {
        o8[e] = (v[e] - mean) * rstd * gg[e] + bb[e];
        sv[e] = (short)f2bf(o8[e]);
      }
      *(short8*)(&Xw[r * LDS_W + d0]) = sv;
      if (bx == 0 && grow >= by * 32 && grow < by * 32 + 32) {
        *(float4*)(x2_out + (size_t)grow * DIM + d0) =
            make_float4(o8[0], o8[1], o8[2], o8[3]);
        *(float4*)(x2_out + (size_t)grow * DIM + d0 + 4) =
            make_float4(o8[4], o8[5], o8[6], o8[7]);
      }
    }
  }
  stage_tile(W, Ws, bx, tid);
  __syncthreads();

  // banded attention over the window (band entirely inside window)
  for (int li = wave; li < 32; li += 4) {
    const int i = by * 32 + li;
    const int lq = i - wlo;
    float qv[8];
    {
      const short8 qs = *(const short8*)(&Xw[lq * LDS_W + d0]);
#pragma unroll
      for (int e = 0; e < 8; ++e) qv[e] = bf2f(qs[e]);
    }
    const int jlo = (i - 4 > 0) ? i - 4 : 0;
    const int jhi = (i + 4 < S_Q - 1) ? i + 4 : S_Q - 1;
    const int n = jhi - jlo + 1;
    float sc[9];
#pragma unroll
    for (int k = 0; k < 9; ++k) {
      if (k < n) {
        const int lk = jlo + k - wlo;
        const short8 ks = *(const short8*)(&Xw[lk * LDS_W + d0]);
        float dd = 0.f;
#pragma unroll
        for (int e = 0; e < 8; ++e) dd += qv[e] * bf2f(ks[e]);
        sc[k] = dd;
      } else {
        sc[k] = 0.f;
      }
    }
#pragma unroll
    for (int o = 32; o > 0; o >>= 1)
#pragma unroll
      for (int k = 0; k < 9; ++k) sc[k] += __shfl_xor(sc[k], o);
    float M = -1e30f;
#pragma unroll
    for (int k = 0; k < 9; ++k) {
      sc[k] *= SCALE_F;
      if (k < n) M = fmaxf(M, sc[k]);
    }
    float p[9], den = 0.f;
#pragma unroll
    for (int k = 0; k < 9; ++k) {
      p[k] = (k < n) ? __expf(sc[k] - M) : 0.f;
      den += p[k];
    }
    const float inv = 1.f / den;
    float o8[8] = {0.f, 0.f, 0.f, 0.f, 0.f, 0.f, 0.f, 0.f};
#pragma unroll
    for (int k = 0; k < 9; ++k) {
      if (k < n) {
        const int lk = jlo + k - wlo;
        const short8 ks = *(const short8*)(&Xw[lk * LDS_W + d0]);
#pragma unroll
        for (int e = 0; e < 8; ++e) o8[e] += p[k] * bf2f(ks[e]);
      }
    }
    short8 sv;
#pragma unroll
    for (int e = 0; e < 8; ++e) sv[e] = (short)f2bf(fmaxf(o8[e] * inv, 0.f));
    *(short8*)(&As[li * LDS_W + d0]) = sv;
  }
  __syncthreads();
  gemm_core<false>(As, Ws, bias, C, bx, by, wave, lane);
}

// ---------------------------------------------------------------------------
// Final: out = LN(y1 + f2).
// ---------------------------------------------------------------------------
__global__ __launch_bounds__(256) void k_addln(
    const float* __restrict__ X, const float* __restrict__ R,
    const float* __restrict__ g, const float* __restrict__ b,
    float* __restrict__ out) {
  const int row = blockIdx.x * 4 + (threadIdx.x >> 6);
  const int lane = threadIdx.x & 63;
  const int d = lane * 8;
  const float4* xp = (const float4*)(X + (size_t)row * DIM + d);
  const float4* rp = (const float4*)(R + (size_t)row * DIM + d);
  float4 x0 = xp[0], x1 = xp[1], r0 = rp[0], r1 = rp[1];
  float v[8] = {x0.x + r0.x, x0.y + r0.y, x0.z + r0.z, x0.w + r0.w,
                x1.x + r1.x, x1.y + r1.y, x1.z + r1.z, x1.w + r1.w};
  float s = 0.f, sq = 0.f;
#pragma unroll
  for (int e = 0; e < 8; ++e) { s += v[e]; sq += v[e] * v[e]; }
  s = wave_sum(s);
  sq = wave_sum(sq);
  const float mean = s * (1.f / DIM);
  const float var = sq * (1.f / DIM) - mean * mean;
  const float rstd = rsqrtf(var + 1e-5f);
  const float4* gp = (const float4*)(g + d);
  const float4* bp = (const float4*)(b + d);
  float4 g0 = gp[0], g1 = gp[1], bb0 = bp[0], bb1 = bp[1];
  float4 o0, o1;
  o0.x = (v[0] - mean) * rstd * g0.x + bb0.x;
  o0.y = (v[1] - mean) * rstd * g0.y + bb0.y;
  o0.z = (v[2] - mean) * rstd * g0.z + bb0.z;
  o0.w = (v[3] - mean) * rstd * g0.w + bb0.w;
  o1.x = (v[4] - mean) * rstd * g1.x + bb1.x;
  o1.y = (v[5] - mean) * rstd * g1.y + bb1.y;
  o1.z = (v[6] - mean) * rstd * g1.z + bb1.z;
  o1.w = (v[7] - mean) * rstd * g1.w + bb1.w;
  *(float4*)(out + (size_t)row * DIM + d) = o0;
  *(float4*)(out + (size_t)row * DIM + d + 4) = o1;
}

// ---------------------------------------------------------------------------
extern "C" void kernel_launch(void* const* d_in, const int* in_sizes, int n_in,
                              void* d_out, int out_size, void* d_ws, size_t ws_size,
                              hipStream_t stream) {
  const float* tgt       = (const float*)d_in[0];
  const float* memory    = (const float*)d_in[1];
  const float* pos       = (const float*)d_in[2];
  const float* qpos      = (const float*)d_in[3];
  // d_in[4] action_idx: analytically t/64, unused
  const float* ca_t2l_w  = (const float*)d_in[5];
  const float* ca_t2l_b  = (const float*)d_in[6];
  const float* ca_l1_w   = (const float*)d_in[7];
  const float* ca_l1_b   = (const float*)d_in[8];
  const float* ca_l2_w   = (const float*)d_in[9];
  const float* ca_l2_b   = (const float*)d_in[10];
  const float* ca_n2_g   = (const float*)d_in[11];
  const float* ca_n2_b   = (const float*)d_in[12];
  const float* ca_n3_g   = (const float*)d_in[13];
  const float* ca_n3_b   = (const float*)d_in[14];
  const float* sa_conv_w = (const float*)d_in[15];
  const float* sa_conv_b = (const float*)d_in[16];
  const float* sa_l1_w   = (const float*)d_in[17];
  const float* sa_l1_b   = (const float*)d_in[18];
  const float* sa_l2_w   = (const float*)d_in[19];
  const float* sa_l2_b   = (const float*)d_in[20];
  const float* sa_n1_g   = (const float*)d_in[21];
  const float* sa_n1_b   = (const float*)d_in[22];
  const float* sa_n2_g   = (const float*)d_in[23];
  const float* sa_n2_b   = (const float*)d_in[24];
  float* out = (float*)d_out;
  float* ws = (float*)d_ws;

  // workspace (floats). part region [0,396288) dead after G1; 1MB activation
  // buffers aliased by lifetime. Peak 4.73 MB.
  unsigned short* part_acc = (unsigned short*)ws;  // 512*3*512 bf16 = 1.5MB
  float* part_ms = ws + 393216;                    // 512*3*2
  float* t2 = ws + 396288;
  float* h  = ws + 658432;
  float* x  = ws + 920576;
  float* f  = ws + 0;        // after G1 (part dead)
  float* x2 = ws + 396288;   // after G2 (t2 dead)
  float* c  = ws + 658432;   // after G3 (h dead)
  float* y1 = ws + 0;        // after G4 (f dead)
  float* h2 = ws + 920576;   // after G4 (x dead)
  float* f2 = ws + 396288;   // after G5 (x2 dead)

  const dim3 gg(16, 16, 1);

  k_ca_partial<<<512, 256, 0, stream>>>(tgt, qpos, memory, pos, part_acc, part_ms);
  k_g1<<<gg, 256, 0, stream>>>(part_acc, part_ms, ca_t2l_w, ca_t2l_b, t2);
  k_gln<<<gg, 256, 0, stream>>>(tgt, t2, ca_n2_g, ca_n2_b, ca_l1_w, ca_l1_b, h, x);
  k_gplain<<<gg, 256, 0, stream>>>(h, ca_l2_w, ca_l2_b, f);
  k_g4<<<gg, 256, 0, stream>>>(x, f, ca_n3_g, ca_n3_b, sa_conv_w, sa_conv_b, c, x2);
  k_gln<<<gg, 256, 0, stream>>>(x2, c, sa_n1_g, sa_n1_b, sa_l1_w, sa_l1_b, h2, y1);
  k_gplain<<<gg, 256, 0, stream>>>(h2, sa_l2_w, sa_l2_b, f2);
  k_addln<<<128, 256, 0, stream>>>(f2, y1, sa_n2_g, sa_n2_b, out);
}

// Round 4
// 281.203 us; speedup vs baseline: 1.2681x; 1.0389x over previous
//
#include <hip/hip_runtime.h>

#define S_Q 512
#define DIM 512
#define SCALE_F 0.04419417382415922f  // 1/sqrt(512)
#define LDS_W 520                     // LDS row stride in shorts (breaks pow2 aliasing)

typedef short short8 __attribute__((ext_vector_type(8)));
typedef float floatx4 __attribute__((ext_vector_type(4)));

__device__ __forceinline__ float wave_sum(float v) {
#pragma unroll
  for (int o = 32; o > 0; o >>= 1) v += __shfl_xor(v, o);
  return v;
}
__device__ __forceinline__ unsigned short f2bf(float f) {
  unsigned u = __float_as_uint(f);
  return (unsigned short)((u + 0x7FFFu + ((u >> 16) & 1u)) >> 16);
}
__device__ __forceinline__ float bf2f(short s) {
  return __uint_as_float(((unsigned)(unsigned short)s) << 16);
}

// ---------------------------------------------------------------------------
// K1: cross-attention partials. One block per 64-frame segment j; queries
// j-1,j,j+1. Wave handles 16 frames in 4 batches of 4.
// ---------------------------------------------------------------------------
__global__ __launch_bounds__(256) void k_ca_partial(
    const float* __restrict__ tgt, const float* __restrict__ qpos,
    const float* __restrict__ mem, const float* __restrict__ pos,
    unsigned short* __restrict__ part_acc, float* __restrict__ part_ms) {
  const int j = blockIdx.x;
  const int tid = threadIdx.x;
  const int wave = tid >> 6, lane = tid & 63;
  const int d0 = lane * 8;
  __shared__ float wacc[4][3][DIM];
  __shared__ float wms[4][3][2];

  float qf[3][8];
#pragma unroll
  for (int c = 0; c < 3; ++c) {
    const int qi = j - 1 + c;
    if ((unsigned)qi < (unsigned)S_Q) {
      float4 t0 = *(const float4*)(tgt + (size_t)qi * DIM + d0);
      float4 t1 = *(const float4*)(tgt + (size_t)qi * DIM + d0 + 4);
      float4 q0 = *(const float4*)(qpos + (size_t)qi * DIM + d0);
      float4 q1 = *(const float4*)(qpos + (size_t)qi * DIM + d0 + 4);
      qf[c][0] = t0.x + q0.x; qf[c][1] = t0.y + q0.y;
      qf[c][2] = t0.z + q0.z; qf[c][3] = t0.w + q0.w;
      qf[c][4] = t1.x + q1.x; qf[c][5] = t1.y + q1.y;
      qf[c][6] = t1.z + q1.z; qf[c][7] = t1.w + q1.w;
    } else {
#pragma unroll
      for (int e = 0; e < 8; ++e) qf[c][e] = 0.f;
    }
  }

  float m[3] = {-1e30f, -1e30f, -1e30f};
  float ssum[3] = {0.f, 0.f, 0.f};
  float acc[3][8];
#pragma unroll
  for (int c = 0; c < 3; ++c)
#pragma unroll
    for (int e = 0; e < 8; ++e) acc[c][e] = 0.f;

  const float* mbase = mem + ((size_t)j * 64 + wave * 16) * DIM + d0;
  const float* pbase = pos + ((size_t)j * 64 + wave * 16) * DIM + d0;

  for (int b = 0; b < 4; ++b) {
    float mv[4][8], kk[4][8];
#pragma unroll
    for (int f = 0; f < 4; ++f) {
      const float* mp = mbase + (size_t)(b * 4 + f) * DIM;
      const float* pp = pbase + (size_t)(b * 4 + f) * DIM;
      float4 a = *(const float4*)mp;
      float4 bb = *(const float4*)(mp + 4);
      float4 c4 = *(const float4*)pp;
      float4 dd = *(const float4*)(pp + 4);
      mv[f][0] = a.x;  mv[f][1] = a.y;  mv[f][2] = a.z;  mv[f][3] = a.w;
      mv[f][4] = bb.x; mv[f][5] = bb.y; mv[f][6] = bb.z; mv[f][7] = bb.w;
      kk[f][0] = a.x + c4.x;  kk[f][1] = a.y + c4.y;
      kk[f][2] = a.z + c4.z;  kk[f][3] = a.w + c4.w;
      kk[f][4] = bb.x + dd.x; kk[f][5] = bb.y + dd.y;
      kk[f][6] = bb.z + dd.z; kk[f][7] = bb.w + dd.w;
    }
    float dots[3][4];
#pragma unroll
    for (int f = 0; f < 4; ++f) {
      float s0 = 0.f, s1 = 0.f, s2 = 0.f;
#pragma unroll
      for (int e = 0; e < 8; ++e) {
        s0 += qf[0][e] * kk[f][e];
        s1 += qf[1][e] * kk[f][e];
        s2 += qf[2][e] * kk[f][e];
      }
      dots[0][f] = s0; dots[1][f] = s1; dots[2][f] = s2;
    }
#pragma unroll
    for (int o = 32; o > 0; o >>= 1)
#pragma unroll
      for (int c = 0; c < 3; ++c)
#pragma unroll
        for (int f = 0; f < 4; ++f) dots[c][f] += __shfl_xor(dots[c][f], o);
#pragma unroll
    for (int c = 0; c < 3; ++c) {
      float s[4];
#pragma unroll
      for (int f = 0; f < 4; ++f) s[f] = dots[c][f] * SCALE_F;
      const float bm = fmaxf(fmaxf(s[0], s[1]), fmaxf(s[2], s[3]));
      const float nm = fmaxf(m[c], bm);
      const float fct = __expf(m[c] - nm);
      m[c] = nm;
      ssum[c] *= fct;
#pragma unroll
      for (int e = 0; e < 8; ++e) acc[c][e] *= fct;
#pragma unroll
      for (int f = 0; f < 4; ++f) {
        const float w = __expf(s[f] - nm);
        ssum[c] += w;
#pragma unroll
        for (int e = 0; e < 8; ++e) acc[c][e] += w * mv[f][e];
      }
    }
  }

#pragma unroll
  for (int c = 0; c < 3; ++c) {
    *(float4*)(&wacc[wave][c][d0]) =
        make_float4(acc[c][0], acc[c][1], acc[c][2], acc[c][3]);
    *(float4*)(&wacc[wave][c][d0 + 4]) =
        make_float4(acc[c][4], acc[c][5], acc[c][6], acc[c][7]);
    if (lane == 0) { wms[wave][c][0] = m[c]; wms[wave][c][1] = ssum[c]; }
  }
  __syncthreads();

  const int d = tid * 2;
#pragma unroll
  for (int c = 0; c < 3; ++c) {
    const int qi = j - 1 + c;
    if ((unsigned)qi >= (unsigned)S_Q) continue;
    float M = wms[0][c][0];
#pragma unroll
    for (int w = 1; w < 4; ++w) M = fmaxf(M, wms[w][c][0]);
    float S = 0.f, ax = 0.f, ay = 0.f;
#pragma unroll
    for (int w = 0; w < 4; ++w) {
      const float wg = __expf(wms[w][c][0] - M);
      S += wg * wms[w][c][1];
      const float2 a = *(const float2*)(&wacc[w][c][d]);
      ax += wg * a.x;
      ay += wg * a.y;
    }
    const size_t slot = (size_t)qi * 3 + c;
    unsigned short* dst = part_acc + slot * DIM + d;
    dst[0] = f2bf(ax);
    dst[1] = f2bf(ay);
    if (tid == 0) {
      part_ms[slot * 2 + 0] = M;
      part_ms[slot * 2 + 1] = S;
    }
  }
}

// ---------------------------------------------------------------------------
// Shared GEMM pieces. Tile: 32(M) x 32(N), K=512 fully LDS-resident (bf16).
// stage_tile: WAVE-COALESCED — wave w covers row 4u+w, lane covers 8
// consecutive floats at col lane*8 (adjacent lanes adjacent addresses).
// The previous per-lane-64-float-chunk layout made every dwordx4 gather 64
// distinct cache lines (~30 us/kernel).
// ---------------------------------------------------------------------------
__device__ __forceinline__ void stage_tile(const float* __restrict__ G,
                                           short* __restrict__ Ls,
                                           int rowblk, int tid) {
  const int w = tid >> 6, lane = tid & 63;
  const int col = lane * 8;
#pragma unroll
  for (int u = 0; u < 8; ++u) {
    const int row = u * 4 + w;
    const float* src = G + (size_t)(rowblk * 32 + row) * DIM + col;
    float4 a = *(const float4*)src;
    float4 b = *(const float4*)(src + 4);
    short8 s;
    s[0] = (short)f2bf(a.x); s[1] = (short)f2bf(a.y);
    s[2] = (short)f2bf(a.z); s[3] = (short)f2bf(a.w);
    s[4] = (short)f2bf(b.x); s[5] = (short)f2bf(b.y);
    s[6] = (short)f2bf(b.z); s[7] = (short)f2bf(b.w);
    *(short8*)(&Ls[row * LDS_W + col]) = s;
  }
}

template <bool RELU>
__device__ __forceinline__ void gemm_core(const short* __restrict__ As,
                                          const short* __restrict__ Ws,
                                          const float* __restrict__ bias,
                                          float* __restrict__ C, int bx, int by,
                                          int wave, int lane) {
  const int r0 = (wave >> 1) * 16, c0 = (wave & 1) * 16;
  const int frow = lane & 15, fk = (lane >> 4) * 8;
  const short* ap = &As[(r0 + frow) * LDS_W + fk];
  const short* wp = &Ws[(c0 + frow) * LDS_W + fk];
  floatx4 acc = {0.f, 0.f, 0.f, 0.f};
#pragma unroll
  for (int kc = 0; kc < 16; ++kc) {
    const short8 af = *(const short8*)(ap + kc * 32);
    const short8 wf = *(const short8*)(wp + kc * 32);
    acc = __builtin_amdgcn_mfma_f32_16x16x32_bf16(af, wf, acc, 0, 0, 0);
  }
  const int col = bx * 32 + c0 + frow;
  const int rowb = by * 32 + r0 + (lane >> 4) * 4;
  const float b = bias[col];
#pragma unroll
  for (int r = 0; r < 4; ++r) {
    float v = acc[r] + b;
    if (RELU) v = fmaxf(v, 0.f);
    C[(size_t)(rowb + r) * DIM + col] = v;
  }
}

// LN prologue: As[r] = bf16(LN(X[row]+R[row])*g+b) for 32 rows; optionally
// write fp32 LN result to x_out (bx==0 blocks).
__device__ __forceinline__ void ln_prologue(const float* __restrict__ X,
                                            const float* __restrict__ R,
                                            const float* __restrict__ g,
                                            const float* __restrict__ b,
                                            short* __restrict__ As, int by,
                                            float* x_out, int wave, int lane) {
  const int d0 = lane * 8;
  float gg[8], bb[8];
  {
    float4 g0 = *(const float4*)(g + d0);
    float4 g1 = *(const float4*)(g + d0 + 4);
    float4 b0 = *(const float4*)(b + d0);
    float4 b1 = *(const float4*)(b + d0 + 4);
    gg[0] = g0.x; gg[1] = g0.y; gg[2] = g0.z; gg[3] = g0.w;
    gg[4] = g1.x; gg[5] = g1.y; gg[6] = g1.z; gg[7] = g1.w;
    bb[0] = b0.x; bb[1] = b0.y; bb[2] = b0.z; bb[3] = b0.w;
    bb[4] = b1.x; bb[5] = b1.y; bb[6] = b1.z; bb[7] = b1.w;
  }
  for (int r = wave; r < 32; r += 4) {
    const int grow = by * 32 + r;
    const float* xp = X + (size_t)grow * DIM + d0;
    const float* rp = R + (size_t)grow * DIM + d0;
    float4 x0 = *(const float4*)xp;
    float4 x1 = *(const float4*)(xp + 4);
    float4 r0 = *(const float4*)rp;
    float4 r1 = *(const float4*)(rp + 4);
    float v[8] = {x0.x + r0.x, x0.y + r0.y, x0.z + r0.z, x0.w + r0.w,
                  x1.x + r1.x, x1.y + r1.y, x1.z + r1.z, x1.w + r1.w};
    float s = 0.f, sq = 0.f;
#pragma unroll
    for (int e = 0; e < 8; ++e) { s += v[e]; sq += v[e] * v[e]; }
#pragma unroll
    for (int o = 32; o > 0; o >>= 1) {
      s += __shfl_xor(s, o);
      sq += __shfl_xor(sq, o);
    }
    const float mean = s * (1.f / DIM);
    const float var = sq * (1.f / DIM) - mean * mean;
    const float rstd = rsqrtf(var + 1e-5f);
    float o8[8];
    short8 sv;
#pragma unroll
    for (int e = 0; e < 8; ++e) {
      o8[e] = (v[e] - mean) * rstd * gg[e] + bb[e];
      sv[e] = (short)f2bf(o8[e]);
    }
    *(short8*)(&As[r * LDS_W + d0]) = sv;
    if (x_out) {
      *(float4*)(x_out + (size_t)grow * DIM + d0) =
          make_float4(o8[0], o8[1], o8[2], o8[3]);
      *(float4*)(x_out + (size_t)grow * DIM + d0 + 4) =
          make_float4(o8[4], o8[5], o8[6], o8[7]);
    }
  }
}

// ---------------------------------------------------------------------------
// G1: combine partials (finish softmax) + ReLU  ->  GEMM with ca_t2l_w.
// ---------------------------------------------------------------------------
__global__ __launch_bounds__(256) void k_g1(
    const unsigned short* __restrict__ part_acc,
    const float* __restrict__ part_ms, const float* __restrict__ W,
    const float* __restrict__ bias, float* __restrict__ C) {
  __shared__ short As[32 * LDS_W];
  __shared__ short Ws[32 * LDS_W];
  const int tid = threadIdx.x;
  const int bx = blockIdx.x, by = blockIdx.y;
  const int wave = tid >> 6, lane = tid & 63;
  const int d0 = lane * 8;
  for (int r = wave; r < 32; r += 4) {
    const int i = by * 32 + r;
    const bool valid[3] = {i < S_Q - 1, true, i > 0};
    float mm[3], ss[3], M = -1e30f;
#pragma unroll
    for (int c = 0; c < 3; ++c) {
      if (valid[c]) {
        mm[c] = part_ms[((size_t)i * 3 + c) * 2 + 0];
        ss[c] = part_ms[((size_t)i * 3 + c) * 2 + 1];
        M = fmaxf(M, mm[c]);
      } else {
        mm[c] = -1e30f;
        ss[c] = 0.f;
      }
    }
    float den = 0.f, wg[3];
#pragma unroll
    for (int c = 0; c < 3; ++c) {
      wg[c] = valid[c] ? __expf(mm[c] - M) : 0.f;
      den += wg[c] * ss[c];
    }
    const float inv = 1.f / den;
    float o[8] = {0.f, 0.f, 0.f, 0.f, 0.f, 0.f, 0.f, 0.f};
#pragma unroll
    for (int c = 0; c < 3; ++c) {
      if (valid[c]) {
        const short8 pa =
            *(const short8*)(part_acc + ((size_t)i * 3 + c) * DIM + d0);
#pragma unroll
        for (int e = 0; e < 8; ++e) o[e] += wg[c] * bf2f(pa[e]);
      }
    }
    short8 sv;
#pragma unroll
    for (int e = 0; e < 8; ++e) sv[e] = (short)f2bf(fmaxf(o[e] * inv, 0.f));
    *(short8*)(&As[r * LDS_W + d0]) = sv;
  }
  stage_tile(W, Ws, bx, tid);
  __syncthreads();
  gemm_core<false>(As, Ws, bias, C, bx, by, wave, lane);
}

// ---------------------------------------------------------------------------
// G2/G5: LN(X+R) prologue (write x_out when bx==0) -> GEMM (ReLU epilogue).
// ---------------------------------------------------------------------------
__global__ __launch_bounds__(256) void k_gln(
    const float* __restrict__ X, const float* __restrict__ R,
    const float* __restrict__ g, const float* __restrict__ b,
    const float* __restrict__ W, const float* __restrict__ bias,
    float* __restrict__ C, float* __restrict__ x_out) {
  __shared__ short As[32 * LDS_W];
  __shared__ short Ws[32 * LDS_W];
  const int tid = threadIdx.x;
  const int bx = blockIdx.x, by = blockIdx.y;
  const int wave = tid >> 6, lane = tid & 63;
  ln_prologue(X, R, g, b, As, by, (bx == 0) ? x_out : nullptr, wave, lane);
  stage_tile(W, Ws, bx, tid);
  __syncthreads();
  gemm_core<true>(As, Ws, bias, C, bx, by, wave, lane);
}

// ---------------------------------------------------------------------------
// G3/G6: plain GEMM (A fp32 global), no relu.
// ---------------------------------------------------------------------------
__global__ __launch_bounds__(256) void k_gplain(
    const float* __restrict__ A, const float* __restrict__ W,
    const float* __restrict__ bias, float* __restrict__ C) {
  __shared__ short As[32 * LDS_W];
  __shared__ short Ws[32 * LDS_W];
  const int tid = threadIdx.x;
  const int bx = blockIdx.x, by = blockIdx.y;
  const int wave = tid >> 6, lane = tid & 63;
  stage_tile(A, As, by, tid);
  stage_tile(W, Ws, bx, tid);
  __syncthreads();
  gemm_core<false>(As, Ws, bias, C, bx, by, wave, lane);
}

// ---------------------------------------------------------------------------
// G4: x2 = LN(x+f) on a 40-row window (write own rows when bx==0), banded
// self-attention (+/-4) + ReLU -> GEMM with sa_conv_w.
// ---------------------------------------------------------------------------
__global__ __launch_bounds__(256) void k_g4(
    const float* __restrict__ X, const float* __restrict__ R,
    const float* __restrict__ g, const float* __restrict__ b,
    const float* __restrict__ W, const float* __restrict__ bias,
    float* __restrict__ C, float* __restrict__ x2_out) {
  __shared__ short Xw[40 * LDS_W];
  __shared__ short As[32 * LDS_W];
  __shared__ short Ws[32 * LDS_W];
  const int tid = threadIdx.x;
  const int bx = blockIdx.x, by = blockIdx.y;
  const int wave = tid >> 6, lane = tid & 63;
  const int d0 = lane * 8;
  const int wlo = (by * 32 - 4 > 0) ? by * 32 - 4 : 0;
  const int whi = (by * 32 + 35 < S_Q - 1) ? by * 32 + 35 : S_Q - 1;
  const int nw = whi - wlo + 1;

  {
    float gg[8], bb[8];
    float4 g0 = *(const float4*)(g + d0);
    float4 g1 = *(const float4*)(g + d0 + 4);
    float4 b0 = *(const float4*)(b + d0);
    float4 b1 = *(const float4*)(b + d0 + 4);
    gg[0] = g0.x; gg[1] = g0.y; gg[2] = g0.z; gg[3] = g0.w;
    gg[4] = g1.x; gg[5] = g1.y; gg[6] = g1.z; gg[7] = g1.w;
    bb[0] = b0.x; bb[1] = b0.y; bb[2] = b0.z; bb[3] = b0.w;
    bb[4] = b1.x; bb[5] = b1.y; bb[6] = b1.z; bb[7] = b1.w;
    for (int r = wave; r < nw; r += 4) {
      const int grow = wlo + r;
      const float* xp = X + (size_t)grow * DIM + d0;
      const float* rp = R + (size_t)grow * DIM + d0;
      float4 x0 = *(const float4*)xp;
      float4 x1 = *(const float4*)(xp + 4);
      float4 r0 = *(const float4*)rp;
      float4 r1 = *(const float4*)(rp + 4);
      float v[8] = {x0.x + r0.x, x0.y + r0.y, x0.z + r0.z, x0.w + r0.w,
                    x1.x + r1.x, x1.y + r1.y, x1.z + r1.z, x1.w + r1.w};
      float s = 0.f, sq = 0.f;
#pragma unroll
      for (int e = 0; e < 8; ++e) { s += v[e]; sq += v[e] * v[e]; }
#pragma unroll
      for (int o = 32; o > 0; o >>= 1) {
        s += __shfl_xor(s, o);
        sq += __shfl_xor(sq, o);
      }
      const float mean = s * (1.f / DIM);
      const float var = sq * (1.f / DIM) - mean * mean;
      const float rstd = rsqrtf(var + 1e-5f);
      float o8[8];
      short8 sv;
#pragma unroll
      for (int e = 0; e < 8; ++e) {
        o8[e] = (v[e] - mean) * rstd * gg[e] + bb[e];
        sv[e] = (short)f2bf(o8[e]);
      }
      *(short8*)(&Xw[r * LDS_W + d0]) = sv;
      if (bx == 0 && grow >= by * 32 && grow < by * 32 + 32) {
        *(float4*)(x2_out + (size_t)grow * DIM + d0) =
            make_float4(o8[0], o8[1], o8[2], o8[3]);
        *(float4*)(x2_out + (size_t)grow * DIM + d0 + 4) =
            make_float4(o8[4], o8[5], o8[6], o8[7]);
      }
    }
  }
  stage_tile(W, Ws, bx, tid);
  __syncthreads();

  for (int li = wave; li < 32; li += 4) {
    const int i = by * 32 + li;
    const int lq = i - wlo;
    float qv[8];
    {
      const short8 qs = *(const short8*)(&Xw[lq * LDS_W + d0]);
#pragma unroll
      for (int e = 0; e < 8; ++e) qv[e] = bf2f(qs[e]);
    }
    const int jlo = (i - 4 > 0) ? i - 4 : 0;
    const int jhi = (i + 4 < S_Q - 1) ? i + 4 : S_Q - 1;
    const int n = jhi - jlo + 1;
    float sc[9];
#pragma unroll
    for (int k = 0; k < 9; ++k) {
      if (k < n) {
        const int lk = jlo + k - wlo;
        const short8 ks = *(const short8*)(&Xw[lk * LDS_W + d0]);
        float dd = 0.f;
#pragma unroll
        for (int e = 0; e < 8; ++e) dd += qv[e] * bf2f(ks[e]);
        sc[k] = dd;
      } else {
        sc[k] = 0.f;
      }
    }
#pragma unroll
    for (int o = 32; o > 0; o >>= 1)
#pragma unroll
      for (int k = 0; k < 9; ++k) sc[k] += __shfl_xor(sc[k], o);
    float M = -1e30f;
#pragma unroll
    for (int k = 0; k < 9; ++k) {
      sc[k] *= SCALE_F;
      if (k < n) M = fmaxf(M, sc[k]);
    }
    float p[9], den = 0.f;
#pragma unroll
    for (int k = 0; k < 9; ++k) {
      p[k] = (k < n) ? __expf(sc[k] - M) : 0.f;
      den += p[k];
    }
    const float inv = 1.f / den;
    float o8[8] = {0.f, 0.f, 0.f, 0.f, 0.f, 0.f, 0.f, 0.f};
#pragma unroll
    for (int k = 0; k < 9; ++k) {
      if (k < n) {
        const int lk = jlo + k - wlo;
        const short8 ks = *(const short8*)(&Xw[lk * LDS_W + d0]);
#pragma unroll
        for (int e = 0; e < 8; ++e) o8[e] += p[k] * bf2f(ks[e]);
      }
    }
    short8 sv;
#pragma unroll
    for (int e = 0; e < 8; ++e) sv[e] = (short)f2bf(fmaxf(o8[e] * inv, 0.f));
    *(short8*)(&As[li * LDS_W + d0]) = sv;
  }
  __syncthreads();
  gemm_core<false>(As, Ws, bias, C, bx, by, wave, lane);
}

// ---------------------------------------------------------------------------
// Final: out = LN(y1 + f2).
// ---------------------------------------------------------------------------
__global__ __launch_bounds__(256) void k_addln(
    const float* __restrict__ X, const float* __restrict__ R,
    const float* __restrict__ g, const float* __restrict__ b,
    float* __restrict__ out) {
  const int row = blockIdx.x * 4 + (threadIdx.x >> 6);
  const int lane = threadIdx.x & 63;
  const int d = lane * 8;
  const float4* xp = (const float4*)(X + (size_t)row * DIM + d);
  const float4* rp = (const float4*)(R + (size_t)row * DIM + d);
  float4 x0 = xp[0], x1 = xp[1], r0 = rp[0], r1 = rp[1];
  float v[8] = {x0.x + r0.x, x0.y + r0.y, x0.z + r0.z, x0.w + r0.w,
                x1.x + r1.x, x1.y + r1.y, x1.z + r1.z, x1.w + r1.w};
  float s = 0.f, sq = 0.f;
#pragma unroll
  for (int e = 0; e < 8; ++e) { s += v[e]; sq += v[e] * v[e]; }
  s = wave_sum(s);
  sq = wave_sum(sq);
  const float mean = s * (1.f / DIM);
  const float var = sq * (1.f / DIM) - mean * mean;
  const float rstd = rsqrtf(var + 1e-5f);
  const float4* gp = (const float4*)(g + d);
  const float4* bp = (const float4*)(b + d);
  float4 g0 = gp[0], g1 = gp[1], bb0 = bp[0], bb1 = bp[1];
  float4 o0, o1;
  o0.x = (v[0] - mean) * rstd * g0.x + bb0.x;
  o0.y = (v[1] - mean) * rstd * g0.y + bb0.y;
  o0.z = (v[2] - mean) * rstd * g0.z + bb0.z;
  o0.w = (v[3] - mean) * rstd * g0.w + bb0.w;
  o1.x = (v[4] - mean) * rstd * g1.x + bb1.x;
  o1.y = (v[5] - mean) * rstd * g1.y + bb1.y;
  o1.z = (v[6] - mean) * rstd * g1.z + bb1.z;
  o1.w = (v[7] - mean) * rstd * g1.w + bb1.w;
  *(float4*)(out + (size_t)row * DIM + d) = o0;
  *(float4*)(out + (size_t)row * DIM + d + 4) = o1;
}

// ---------------------------------------------------------------------------
extern "C" void kernel_launch(void* const* d_in, const int* in_sizes, int n_in,
                              void* d_out, int out_size, void* d_ws, size_t ws_size,
                              hipStream_t stream) {
  const float* tgt       = (const float*)d_in[0];
  const float* memory    = (const float*)d_in[1];
  const float* pos       = (const float*)d_in[2];
  const float* qpos      = (const float*)d_in[3];
  // d_in[4] action_idx: analytically t/64, unused
  const float* ca_t2l_w  = (const float*)d_in[5];
  const float* ca_t2l_b  = (const float*)d_in[6];
  const float* ca_l1_w   = (const float*)d_in[7];
  const float* ca_l1_b   = (const float*)d_in[8];
  const float* ca_l2_w   = (const float*)d_in[9];
  const float* ca_l2_b   = (const float*)d_in[10];
  const float* ca_n2_g   = (const float*)d_in[11];
  const float* ca_n2_b   = (const float*)d_in[12];
  const float* ca_n3_g   = (const float*)d_in[13];
  const float* ca_n3_b   = (const float*)d_in[14];
  const float* sa_conv_w = (const float*)d_in[15];
  const float* sa_conv_b = (const float*)d_in[16];
  const float* sa_l1_w   = (const float*)d_in[17];
  const float* sa_l1_b   = (const float*)d_in[18];
  const float* sa_l2_w   = (const float*)d_in[19];
  const float* sa_l2_b   = (const float*)d_in[20];
  const float* sa_n1_g   = (const float*)d_in[21];
  const float* sa_n1_b   = (const float*)d_in[22];
  const float* sa_n2_g   = (const float*)d_in[23];
  const float* sa_n2_b   = (const float*)d_in[24];
  float* out = (float*)d_out;
  float* ws = (float*)d_ws;

  // workspace (floats). part region [0,396288) dead after G1; 1MB activation
  // buffers aliased by lifetime. Peak 4.73 MB.
  unsigned short* part_acc = (unsigned short*)ws;  // 512*3*512 bf16 = 1.5MB
  float* part_ms = ws + 393216;                    // 512*3*2
  float* t2 = ws + 396288;
  float* h  = ws + 658432;
  float* x  = ws + 920576;
  float* f  = ws + 0;        // after G1 (part dead)
  float* x2 = ws + 396288;   // after G2 (t2 dead)
  float* c  = ws + 658432;   // after G3 (h dead)
  float* y1 = ws + 0;        // after G4 (f dead)
  float* h2 = ws + 920576;   // after G4 (x dead)
  float* f2 = ws + 396288;   // after G5 (x2 dead)

  const dim3 gg(16, 16, 1);

  k_ca_partial<<<512, 256, 0, stream>>>(tgt, qpos, memory, pos, part_acc, part_ms);
  k_g1<<<gg, 256, 0, stream>>>(part_acc, part_ms, ca_t2l_w, ca_t2l_b, t2);
  k_gln<<<gg, 256, 0, stream>>>(tgt, t2, ca_n2_g, ca_n2_b, ca_l1_w, ca_l1_b, h, x);
  k_gplain<<<gg, 256, 0, stream>>>(h, ca_l2_w, ca_l2_b, f);
  k_g4<<<gg, 256, 0, stream>>>(x, f, ca_n3_g, ca_n3_b, sa_conv_w, sa_conv_b, c, x2);
  k_gln<<<gg, 256, 0, stream>>>(x2, c, sa_n1_g, sa_n1_b, sa_l1_w, sa_l1_b, h2, y1);
  k_gplain<<<gg, 256, 0, stream>>>(h2, sa_l2_w, sa_l2_b, f2);
  k_addln<<<128, 256, 0, stream>>>(f2, y1, sa_n2_g, sa_n2_b, out);
}